// Round 14
// baseline (103.569 us; speedup 1.0000x reference)
//
#include <hip/hip_runtime.h>

#define EPS 1e-6f

typedef __attribute__((ext_vector_type(8))) short short8;   // 8 x bf16 bits
typedef __attribute__((ext_vector_type(16))) float f32x16;  // MFMA 32x32 acc

__device__ __forceinline__ float elu1(float x) {
    // elu(x) + 1  ==  x > 0 ? x + 1 : exp(x)
    return x > 0.f ? x + 1.f : __expf(x);
}

// fp32 -> bf16 bits, round-to-nearest-even
__device__ __forceinline__ short f2bf(float x) {
    unsigned u = __float_as_uint(x);
    return (short)((u + 0x7FFFu + ((u >> 16) & 1u)) >> 16);
}

// ---------------------------------------------------------------------------
// Phase 1 (R14): SINGLE-SHOT blocks — the exact profile of out_kernel, which
// moves the byte-identical strided pattern at ~6 TB/s while every loop-
// structured p1 variant pinned at 2.2 TB/s (R5-R13). Root cause model: long-
// lived blocks burst-then-wait at barriers/waitcnts, so per-CU outstanding
// cache-line fills stay low; single-shot blocks with a 4096-deep grid keep
// many waves in their staging burst at any instant.
// Block (nh, 64-row chunk), 256 thr: stage (8 float4 + 4 scalar mask loads
// per thread) -> elu/ksum/ds_write -> __syncthreads -> wave wv MFMAs rows
// [16wv,16wv+16) -> ksum LDS reduce -> acc tree-combine -> wave 0 dumps.
// Fragment mapping (verified R5-R13): A row d=l&31(+32td), k=8*(l>>5)+j;
// B col m=l&31(+32tm); C/D col=l&31, row=(r&3)+8*(r>>2)+4*(l>>5).
// ---------------------------------------------------------------------------
template<int ITERS>
__global__ __launch_bounds__(256, 2) void kv_partial_kernel(
    const float* __restrict__ keys, const float* __restrict__ values,
    const float* __restrict__ mask, float* __restrict__ pkv,
    float* __restrict__ pks)
{
    __shared__ float Kls[64][64];    // 16 KB; reused as combine buf
    __shared__ float Vls[64][64];    // 16 KB; reused as combine buf

    const int nh = blockIdx.x, n = nh >> 4, h = nh & 15;
    const int chunk = blockIdx.y;
    const int t = threadIdx.x, wv = t >> 6, l = t & 63;
    const int half = l >> 5, col = l & 31;
    const int r0 = t >> 4, c4 = (t & 15) * 4;   // staging role

    const int s0 = chunk * (ITERS * 64);
    const float* kb = keys   + ((size_t)(n * 4096 + s0) * 16 + h) * 64;
    const float* vb = values + ((size_t)(n * 4096 + s0) * 16 + h) * 64;
    const float* mb = mask + n * 4096 + s0;

    f32x16 acc[2][2];
    #pragma unroll
    for (int a = 0; a < 2; ++a)
        #pragma unroll
        for (int b = 0; b < 2; ++b)
            #pragma unroll
            for (int r = 0; r < 16; ++r) acc[a][b][r] = 0.f;
    float4 ks4 = make_float4(0.f, 0.f, 0.f, 0.f);

    #pragma unroll
    for (int it = 0; it < ITERS; ++it) {
        // ---- staging burst: 8 float4 + 4 scalar mask loads, all independent
        float4 kr[4], vr[4];
        float mr[4];
        #pragma unroll
        for (int k = 0; k < 4; ++k) {
            const int row = r0 + 16 * k;
            const size_t go = (size_t)(it * 64 + row) * 1024 + c4;
            kr[k] = *(const float4*)(kb + go);
            vr[k] = *(const float4*)(vb + go);
            mr[k] = mb[it * 64 + row];          // 16x redundant: L1 broadcast
        }
        if (it) __syncthreads();                // prior MFMA reads done
        #pragma unroll
        for (int k = 0; k < 4; ++k) {
            const int row = r0 + 16 * k;
            float4 kk = kr[k];
            const float msk = mr[k];
            kk.x = elu1(kk.x) * msk; kk.y = elu1(kk.y) * msk;
            kk.z = elu1(kk.z) * msk; kk.w = elu1(kk.w) * msk;
            ks4.x += kk.x; ks4.y += kk.y; ks4.z += kk.z; ks4.w += kk.w;
            *(float4*)&Kls[row][c4] = kk;
            *(float4*)&Vls[row][c4] = vr[k];
        }
        __syncthreads();
        // ---- compute: wave's 16 rows; scalar LDS reads (2-way bank = free)
        short8 ka0, ka1, va0, va1;
        #pragma unroll
        for (int j = 0; j < 8; ++j) {
            const int s = 16 * wv + 8 * half + j;
            ka0[j] = f2bf(Kls[s][col]);
            ka1[j] = f2bf(Kls[s][col + 32]);
            va0[j] = f2bf(Vls[s][col]);
            va1[j] = f2bf(Vls[s][col + 32]);
        }
        acc[0][0] = __builtin_amdgcn_mfma_f32_32x32x16_bf16(ka0, va0, acc[0][0], 0, 0, 0);
        acc[0][1] = __builtin_amdgcn_mfma_f32_32x32x16_bf16(ka0, va1, acc[0][1], 0, 0, 0);
        acc[1][0] = __builtin_amdgcn_mfma_f32_32x32x16_bf16(ka1, va0, acc[1][0], 0, 0, 0);
        acc[1][1] = __builtin_amdgcn_mfma_f32_32x32x16_bf16(ka1, va1, acc[1][1], 0, 0, 0);
    }

    // ---- ksum block reduce (thread covered cols c4..c4+3 of its rows)
    __syncthreads();
    *(float4*)&Kls[r0][c4] = ks4;            // Ksr[16][64] region
    __syncthreads();
    if (t < 64) {
        float s = 0.f;
        #pragma unroll
        for (int r = 0; r < 16; ++r) s += Kls[r][t];
        pks[((size_t)chunk * 64 + nh) * 64 + t] = s;
    }
    __syncthreads();

    // ---- acc tree-combine across waves (buffers = Kls, Vls; [idx][l])
    float* cb0 = &Kls[0][0];
    float* cb1 = &Vls[0][0];
#define FLATW(BUF)                                                         \
    { _Pragma("unroll") for (int td = 0; td < 2; ++td)                     \
      _Pragma("unroll") for (int tm = 0; tm < 2; ++tm)                     \
      _Pragma("unroll") for (int r = 0; r < 16; ++r)                       \
          BUF[((td * 2 + tm) * 16 + r) * 64 + l] = acc[td][tm][r]; }
#define FLATR(BUF)                                                         \
    { _Pragma("unroll") for (int td = 0; td < 2; ++td)                     \
      _Pragma("unroll") for (int tm = 0; tm < 2; ++tm)                     \
      _Pragma("unroll") for (int r = 0; r < 16; ++r)                       \
          acc[td][tm][r] += BUF[((td * 2 + tm) * 16 + r) * 64 + l]; }
    if (wv == 2) FLATW(cb0);
    if (wv == 3) FLATW(cb1);
    __syncthreads();
    if (wv == 0) FLATR(cb0);
    if (wv == 1) FLATR(cb1);
    __syncthreads();
    if (wv == 1) FLATW(cb0);
    __syncthreads();
    if (wv == 0) {
        FLATR(cb0);
        // dump combined partial in [d][m] order (verified C/D layout)
        float* pb = pkv + ((size_t)chunk * 64 + nh) * 4096;
        #pragma unroll
        for (int td = 0; td < 2; ++td)
            #pragma unroll
            for (int tm = 0; tm < 2; ++tm)
                #pragma unroll
                for (int r = 0; r < 16; ++r) {
                    const int d = 32 * td + (r & 3) + 8 * (r >> 2) + 4 * half;
                    pb[(size_t)d * 64 + 32 * tm + col] = acc[td][tm][r];
                }
    }
#undef FLATW
#undef FLATR
}

// ---------------------------------------------------------------------------
// Reduce: kvt[nh][d][m] = sum_c pkv[c][nh][d][m];  ksum[nh][d] = sum_c pks.
// ---------------------------------------------------------------------------
__global__ __launch_bounds__(256) void kv_reduce_kernel(
    const float* __restrict__ pkv, const float* __restrict__ pks,
    float* __restrict__ kvt, float* __restrict__ ksum, int CH)
{
    const int nh = blockIdx.x;
    const int f4 = blockIdx.y * 256 + threadIdx.x;   // float4 slot 0..1023
    float4 s4 = make_float4(0.f, 0.f, 0.f, 0.f);
    #pragma unroll 4
    for (int c = 0; c < CH; ++c) {
        const float4 v = *(const float4*)(pkv + ((size_t)c * 64 + nh) * 4096 + f4 * 4);
        s4.x += v.x; s4.y += v.y; s4.z += v.z; s4.w += v.w;
    }
    *(float4*)(kvt + (size_t)nh * 4096 + f4 * 4) = s4;

    if (blockIdx.y == 0 && threadIdx.x < 64) {
        float s = 0.f;
        #pragma unroll 4
        for (int c = 0; c < CH; ++c)
            s += pks[((size_t)c * 64 + nh) * 64 + threadIdx.x];
        ksum[nh * 64 + threadIdx.x] = s;
    }
}

// ---------------------------------------------------------------------------
// Phase 2: out[n,l,h,m] = z_l * sum_d Q'[l,d] * KVT[d,m],
//          z_l = 1/(sum_d Q'[l,d]*Ksum[d] + EPS)   (R8 version, ~BW-bound)
// ---------------------------------------------------------------------------
__global__ __launch_bounds__(256) void out_kernel(
    const float* __restrict__ queries, const float* __restrict__ kvt,
    const float* __restrict__ ksum, float* __restrict__ out)
{
    __shared__ float Qs[64][68];    // [l][d]
    __shared__ float KVs[64][68];   // [d][m]
    __shared__ float Ksm[64];

    const int nh = blockIdx.x;
    const int n = nh >> 4, h = nh & 15;
    const int t = threadIdx.x;
    const int l0 = blockIdx.y * 64;

    #pragma unroll
    for (int k = 0; k < 4; ++k) {
        const int idx = t + k * 256;
        *(float4*)&KVs[idx >> 4][(idx & 15) * 4] =
            *(const float4*)(kvt + (size_t)nh * 4096 + idx * 4);
    }
    if (t < 64) Ksm[t] = ksum[nh * 64 + t];

    #pragma unroll
    for (int k = 0; k < 4; ++k) {
        const int idx = t + k * 256;
        const int row = idx >> 4, seg = idx & 15;
        const size_t g = ((size_t)(n * 4096 + l0 + row) * 16 + h) * 64 + seg * 4;
        float4 q4 = *(const float4*)(queries + g);
        q4.x = elu1(q4.x);
        q4.y = elu1(q4.y);
        q4.z = elu1(q4.z);
        q4.w = elu1(q4.w);
        *(float4*)&Qs[row][seg * 4] = q4;
    }
    __syncthreads();

    const int mg = t & 7;          // m cols 4mg..+3 and 32+4mg..+3
    const int lg = t >> 3;         // 0..31; rows lg, lg+32

    float acc[2][8];
    float zacc[2] = {0.f, 0.f};
    #pragma unroll
    for (int i = 0; i < 2; ++i)
        #pragma unroll
        for (int j = 0; j < 8; ++j) acc[i][j] = 0.f;

    #pragma unroll 4
    for (int d0 = 0; d0 < 64; d0 += 4) {
        const float4 km4 = *(const float4*)&Ksm[d0];
        float4 q[2];
        q[0] = *(const float4*)&Qs[lg][d0];
        q[1] = *(const float4*)&Qs[lg + 32][d0];
        #pragma unroll
        for (int i = 0; i < 2; ++i)
            zacc[i] += q[i].x * km4.x + q[i].y * km4.y +
                       q[i].z * km4.z + q[i].w * km4.w;
        #pragma unroll
        for (int r = 0; r < 4; ++r) {
            const float4 kva = *(const float4*)&KVs[d0 + r][mg * 4];
            const float4 kvb = *(const float4*)&KVs[d0 + r][32 + mg * 4];
            #pragma unroll
            for (int i = 0; i < 2; ++i) {
                const float qc = ((const float*)&q[i])[r];
                acc[i][0] = fmaf(qc, kva.x, acc[i][0]);
                acc[i][1] = fmaf(qc, kva.y, acc[i][1]);
                acc[i][2] = fmaf(qc, kva.z, acc[i][2]);
                acc[i][3] = fmaf(qc, kva.w, acc[i][3]);
                acc[i][4] = fmaf(qc, kvb.x, acc[i][4]);
                acc[i][5] = fmaf(qc, kvb.y, acc[i][5]);
                acc[i][6] = fmaf(qc, kvb.z, acc[i][6]);
                acc[i][7] = fmaf(qc, kvb.w, acc[i][7]);
            }
        }
    }

    #pragma unroll
    for (int i = 0; i < 2; ++i) {
        const float z = 1.f / (zacc[i] + EPS);
        const int row = l0 + lg + 32 * i;
        const size_t g = ((size_t)(n * 4096 + row) * 16 + h) * 64;
        float4 o;
        o.x = acc[i][0] * z; o.y = acc[i][1] * z;
        o.z = acc[i][2] * z; o.w = acc[i][3] * z;
        *(float4*)(out + g + mg * 4) = o;
        o.x = acc[i][4] * z; o.y = acc[i][5] * z;
        o.z = acc[i][6] * z; o.w = acc[i][7] * z;
        *(float4*)(out + g + 32 + mg * 4) = o;
    }
}

extern "C" void kernel_launch(void* const* d_in, const int* in_sizes, int n_in,
                              void* d_out, int out_size, void* d_ws, size_t ws_size,
                              hipStream_t stream) {
    const float* queries = (const float*)d_in[0];
    const float* keys    = (const float*)d_in[1];
    const float* values  = (const float*)d_in[2];
    const float* mask    = (const float*)d_in[3];
    float* out = (float*)d_out;

    auto need = [](int CH) {
        return ((size_t)CH * 64 * 4096 + (size_t)CH * 64 * 64 +
                (size_t)64 * 4096 + 64 * 64) * sizeof(float);
    };
    // CH=64 (69MB, ran in R8/R11); fallback CH=32 with 2-tile blocks.
    const int CH = (need(64) <= ws_size) ? 64 : 32;

    float* pkv  = (float*)d_ws;                         // [CH][64][64][64] (d,m)
    float* pks  = pkv + (size_t)CH * 64 * 4096;         // [CH][64][64]
    float* kvt  = pks + (size_t)CH * 64 * 64;           // [64][64][64] (d,m)
    float* ksum = kvt + (size_t)64 * 4096;              // [64][64]

    if (CH == 64)
        kv_partial_kernel<1><<<dim3(64, 64), 256, 0, stream>>>(keys, values, mask, pkv, pks);
    else
        kv_partial_kernel<2><<<dim3(64, 32), 256, 0, stream>>>(keys, values, mask, pkv, pks);
    kv_reduce_kernel<<<dim3(64, 4), 256, 0, stream>>>(pkv, pks, kvt, ksum, CH);
    out_kernel<<<dim3(64, 64), 256, 0, stream>>>(queries, kvt, ksum, out);
}

// Round 15
// 87.583 us; speedup vs baseline: 1.1825x; 1.1825x over previous
//
#include <hip/hip_runtime.h>

#define EPS 1e-6f

typedef __attribute__((ext_vector_type(8))) short short8;   // 8 x bf16 bits
typedef __attribute__((ext_vector_type(16))) float f32x16;  // MFMA 32x32 acc

__device__ __forceinline__ float elu1(float x) {
    // elu(x) + 1  ==  x > 0 ? x + 1 : exp(x)
    return x > 0.f ? x + 1.f : __expf(x);
}

// fp32 -> bf16 bits, round-to-nearest-even
__device__ __forceinline__ short f2bf(float x) {
    unsigned u = __float_as_uint(x);
    return (short)((u + 0x7FFFu + ((u >> 16) & 1u)) >> 16);
}

#define LGKMCNT0() asm volatile("s_waitcnt lgkmcnt(0)" ::: "memory")
// raw barrier: does NOT drain vmcnt (unlike __syncthreads), so global loads
// issued before it stay in flight. lgkmcnt(0) first = LDS ops visible.
#define BAR() do { LGKMCNT0(); __builtin_amdgcn_s_barrier(); \
                   asm volatile("" ::: "memory"); } while (0)

// ---------------------------------------------------------------------------
// Phase 1 (R15 = R13 with ITERS=8/CH=8): tail combine + reduce traffic halved.
// Structure proven best (R13: kv=60us, zero spill).
// ---------------------------------------------------------------------------
template<int ITERS>
__global__ __launch_bounds__(256, 2) void kv_partial_kernel(
    const float* __restrict__ keys, const float* __restrict__ values,
    const float* __restrict__ mask, float* __restrict__ pkv,
    float* __restrict__ pks)
{
    __shared__ float Kls[64][64];    // 16 KB; reused as combine buf
    __shared__ float Vls[64][64];    // 16 KB; reused as combine buf
    __shared__ float Mls[ITERS * 64];

    const int nh = blockIdx.x, n = nh >> 4, h = nh & 15;
    const int chunk = blockIdx.y;
    const int t = threadIdx.x, wv = t >> 6, l = t & 63;
    const int half = l >> 5, col = l & 31;
    const int r0 = t >> 4, c4 = (t & 15) * 4;   // staging role

    const int s0 = chunk * (ITERS * 64);
    const float* kb = keys   + ((size_t)(n * 4096 + s0) * 16 + h) * 64;
    const float* vb = values + ((size_t)(n * 4096 + s0) * 16 + h) * 64;

    if (t < ITERS * 16)
        *(float4*)&Mls[t * 4] = *(const float4*)(mask + n * 4096 + s0 + t * 4);

    f32x16 acc[2][2];
    #pragma unroll
    for (int a = 0; a < 2; ++a)
        #pragma unroll
        for (int b = 0; b < 2; ++b)
            #pragma unroll
            for (int r = 0; r < 16; ++r) acc[a][b][r] = 0.f;
    float4 ks4 = make_float4(0.f, 0.f, 0.f, 0.f);

    float4 kr[4], vr[4];
    #pragma unroll
    for (int k = 0; k < 4; ++k) {     // prologue: tile 0 (8 float4/thread)
        const size_t go = (size_t)(r0 + 16 * k) * 1024 + c4;
        kr[k] = *(const float4*)(kb + go);
        vr[k] = *(const float4*)(vb + go);
    }

    #pragma unroll
    for (int it = 0; it < ITERS; ++it) {
        BAR();   // (A) prior tile's LDS reads done; Mls visible at it==0
        #pragma unroll
        for (int k = 0; k < 4; ++k) {
            const float msk = Mls[it * 64 + r0 + 16 * k];
            float4 kk = kr[k];
            kk.x = elu1(kk.x) * msk; kk.y = elu1(kk.y) * msk;
            kk.z = elu1(kk.z) * msk; kk.w = elu1(kk.w) * msk;
            ks4.x += kk.x; ks4.y += kk.y; ks4.z += kk.z; ks4.w += kk.w;
            *(float4*)&Kls[r0 + 16 * k][c4] = kk;
            *(float4*)&Vls[r0 + 16 * k][c4] = vr[k];
        }
        BAR();   // (B) tile staged & visible
        if (it + 1 < ITERS) {          // issue next tile; stays in flight
            #pragma unroll
            for (int k = 0; k < 4; ++k) {
                const size_t go = (size_t)(r0 + 16 * k + 64 * (it + 1)) * 1024 + c4;
                kr[k] = *(const float4*)(kb + go);
                vr[k] = *(const float4*)(vb + go);
            }
        }
        // compute: wave's 16 rows; scalar LDS reads (2-way bank = free)
        short8 ka0, ka1, va0, va1;
        #pragma unroll
        for (int j = 0; j < 8; ++j) {
            const int s = 16 * wv + 8 * half + j;
            ka0[j] = f2bf(Kls[s][col]);
            ka1[j] = f2bf(Kls[s][col + 32]);
            va0[j] = f2bf(Vls[s][col]);
            va1[j] = f2bf(Vls[s][col + 32]);
        }
        acc[0][0] = __builtin_amdgcn_mfma_f32_32x32x16_bf16(ka0, va0, acc[0][0], 0, 0, 0);
        acc[0][1] = __builtin_amdgcn_mfma_f32_32x32x16_bf16(ka0, va1, acc[0][1], 0, 0, 0);
        acc[1][0] = __builtin_amdgcn_mfma_f32_32x32x16_bf16(ka1, va0, acc[1][0], 0, 0, 0);
        acc[1][1] = __builtin_amdgcn_mfma_f32_32x32x16_bf16(ka1, va1, acc[1][1], 0, 0, 0);
    }

    // ---- ksum block reduce
    BAR();
    *(float4*)&Kls[r0][c4] = ks4;            // Ksr[16][64] region
    BAR();
    if (t < 64) {
        float s = 0.f;
        #pragma unroll
        for (int r = 0; r < 16; ++r) s += Kls[r][t];
        pks[((size_t)chunk * 64 + nh) * 64 + t] = s;
    }
    BAR();

    // ---- acc tree-combine across waves (buffers = Kls, Vls; [idx][l])
    float* cb0 = &Kls[0][0];
    float* cb1 = &Vls[0][0];
#define FLATW(BUF)                                                         \
    { _Pragma("unroll") for (int td = 0; td < 2; ++td)                     \
      _Pragma("unroll") for (int tm = 0; tm < 2; ++tm)                     \
      _Pragma("unroll") for (int r = 0; r < 16; ++r)                       \
          BUF[((td * 2 + tm) * 16 + r) * 64 + l] = acc[td][tm][r]; }
#define FLATR(BUF)                                                         \
    { _Pragma("unroll") for (int td = 0; td < 2; ++td)                     \
      _Pragma("unroll") for (int tm = 0; tm < 2; ++tm)                     \
      _Pragma("unroll") for (int r = 0; r < 16; ++r)                       \
          acc[td][tm][r] += BUF[((td * 2 + tm) * 16 + r) * 64 + l]; }
    if (wv == 2) FLATW(cb0);
    if (wv == 3) FLATW(cb1);
    BAR();
    if (wv == 0) FLATR(cb0);
    if (wv == 1) FLATR(cb1);
    BAR();
    if (wv == 1) FLATW(cb0);
    BAR();
    if (wv == 0) {
        FLATR(cb0);
        float* pb = pkv + ((size_t)chunk * 64 + nh) * 4096;
        #pragma unroll
        for (int td = 0; td < 2; ++td)
            #pragma unroll
            for (int tm = 0; tm < 2; ++tm)
                #pragma unroll
                for (int r = 0; r < 16; ++r) {
                    const int d = 32 * td + (r & 3) + 8 * (r >> 2) + 4 * half;
                    pb[(size_t)d * 64 + 32 * tm + col] = acc[td][tm][r];
                }
    }
#undef FLATW
#undef FLATR
}

// ---------------------------------------------------------------------------
// DIAGNOSTIC PROBE (half-scale): staging skeleton of kv_partial WITHOUT the
// fragment/f2bf/MFMA/combine path. Same loads, same elu+mask+ksum VALU, same
// LDS writes, same barriers, same block shape. One token LDS read/iter keeps
// the staged arrays live (anti-DCE, rule #17); vsum+ksum -> scratch keeps
// everything rooted. Its duration (from total minus known parts) splits:
//   p ~ 25-35us  => skeleton/memory-bound  -> attack staging next
//   p ~  8-12us  => fragment/MFMA path is the wall -> attack fragments next
// ---------------------------------------------------------------------------
template<int ITERS>
__global__ __launch_bounds__(256, 2) void kv_probe_kernel(
    const float* __restrict__ keys, const float* __restrict__ values,
    const float* __restrict__ mask, float* __restrict__ pscr_ks,
    float* __restrict__ pscr_v)
{
    __shared__ float Kls[64][64];
    __shared__ float Vls[64][64];
    __shared__ float Mls[ITERS * 64];

    const int nh = blockIdx.x, n = nh >> 4, h = nh & 15;
    const int chunk = blockIdx.y;
    const int t = threadIdx.x;
    const int r0 = t >> 4, c4 = (t & 15) * 4;

    const int s0 = chunk * (ITERS * 64);
    const float* kb = keys   + ((size_t)(n * 4096 + s0) * 16 + h) * 64;
    const float* vb = values + ((size_t)(n * 4096 + s0) * 16 + h) * 64;

    if (t < ITERS * 16)
        *(float4*)&Mls[t * 4] = *(const float4*)(mask + n * 4096 + s0 + t * 4);

    float4 ks4 = make_float4(0.f, 0.f, 0.f, 0.f);
    float vsum = 0.f;

    float4 kr[4], vr[4];
    #pragma unroll
    for (int k = 0; k < 4; ++k) {
        const size_t go = (size_t)(r0 + 16 * k) * 1024 + c4;
        kr[k] = *(const float4*)(kb + go);
        vr[k] = *(const float4*)(vb + go);
    }

    #pragma unroll
    for (int it = 0; it < ITERS; ++it) {
        BAR();
        #pragma unroll
        for (int k = 0; k < 4; ++k) {
            const float msk = Mls[it * 64 + r0 + 16 * k];
            float4 kk = kr[k];
            kk.x = elu1(kk.x) * msk; kk.y = elu1(kk.y) * msk;
            kk.z = elu1(kk.z) * msk; kk.w = elu1(kk.w) * msk;
            ks4.x += kk.x; ks4.y += kk.y; ks4.z += kk.z; ks4.w += kk.w;
            *(float4*)&Kls[r0 + 16 * k][c4] = kk;
            *(float4*)&Vls[r0 + 16 * k][c4] = vr[k];
        }
        BAR();
        if (it + 1 < ITERS) {
            #pragma unroll
            for (int k = 0; k < 4; ++k) {
                const size_t go = (size_t)(r0 + 16 * k + 64 * (it + 1)) * 1024 + c4;
                kr[k] = *(const float4*)(kb + go);
                vr[k] = *(const float4*)(vb + go);
            }
        }
        // token consume (keeps staged arrays live; 1 LDS read vs real 32)
        vsum += Vls[t & 63][(t * 7) & 63] + Kls[(t * 3) & 63][t & 63];
    }

    BAR();
    *(float4*)&Kls[r0][c4] = ks4;
    BAR();
    if (t < 64) {
        float s = 0.f;
        #pragma unroll
        for (int r = 0; r < 16; ++r) s += Kls[r][t];
        pscr_ks[((size_t)chunk * 64 + nh) * 64 + t] = s;
    }
    pscr_v[((size_t)(chunk * 64 + nh)) * 256 + t] = vsum;
}

// ---------------------------------------------------------------------------
// Reduce: kvt[nh][d][m] = sum_c pkv[c][nh][d][m];  ksum[nh][d] = sum_c pks.
// ---------------------------------------------------------------------------
__global__ __launch_bounds__(256) void kv_reduce_kernel(
    const float* __restrict__ pkv, const float* __restrict__ pks,
    float* __restrict__ kvt, float* __restrict__ ksum, int CH)
{
    const int nh = blockIdx.x;
    const int f4 = blockIdx.y * 256 + threadIdx.x;   // float4 slot 0..1023
    float4 s4 = make_float4(0.f, 0.f, 0.f, 0.f);
    #pragma unroll 4
    for (int c = 0; c < CH; ++c) {
        const float4 v = *(const float4*)(pkv + ((size_t)c * 64 + nh) * 4096 + f4 * 4);
        s4.x += v.x; s4.y += v.y; s4.z += v.z; s4.w += v.w;
    }
    *(float4*)(kvt + (size_t)nh * 4096 + f4 * 4) = s4;

    if (blockIdx.y == 0 && threadIdx.x < 64) {
        float s = 0.f;
        #pragma unroll 4
        for (int c = 0; c < CH; ++c)
            s += pks[((size_t)c * 64 + nh) * 64 + threadIdx.x];
        ksum[nh * 64 + threadIdx.x] = s;
    }
}

// ---------------------------------------------------------------------------
// Phase 2: out (R8 version, ~L3-BW-bound)
// ---------------------------------------------------------------------------
__global__ __launch_bounds__(256) void out_kernel(
    const float* __restrict__ queries, const float* __restrict__ kvt,
    const float* __restrict__ ksum, float* __restrict__ out)
{
    __shared__ float Qs[64][68];    // [l][d]
    __shared__ float KVs[64][68];   // [d][m]
    __shared__ float Ksm[64];

    const int nh = blockIdx.x;
    const int n = nh >> 4, h = nh & 15;
    const int t = threadIdx.x;
    const int l0 = blockIdx.y * 64;

    #pragma unroll
    for (int k = 0; k < 4; ++k) {
        const int idx = t + k * 256;
        *(float4*)&KVs[idx >> 4][(idx & 15) * 4] =
            *(const float4*)(kvt + (size_t)nh * 4096 + idx * 4);
    }
    if (t < 64) Ksm[t] = ksum[nh * 64 + t];

    #pragma unroll
    for (int k = 0; k < 4; ++k) {
        const int idx = t + k * 256;
        const int row = idx >> 4, seg = idx & 15;
        const size_t g = ((size_t)(n * 4096 + l0 + row) * 16 + h) * 64 + seg * 4;
        float4 q4 = *(const float4*)(queries + g);
        q4.x = elu1(q4.x);
        q4.y = elu1(q4.y);
        q4.z = elu1(q4.z);
        q4.w = elu1(q4.w);
        *(float4*)&Qs[row][seg * 4] = q4;
    }
    __syncthreads();

    const int mg = t & 7;          // m cols 4mg..+3 and 32+4mg..+3
    const int lg = t >> 3;         // 0..31; rows lg, lg+32

    float acc[2][8];
    float zacc[2] = {0.f, 0.f};
    #pragma unroll
    for (int i = 0; i < 2; ++i)
        #pragma unroll
        for (int j = 0; j < 8; ++j) acc[i][j] = 0.f;

    #pragma unroll 4
    for (int d0 = 0; d0 < 64; d0 += 4) {
        const float4 km4 = *(const float4*)&Ksm[d0];
        float4 q[2];
        q[0] = *(const float4*)&Qs[lg][d0];
        q[1] = *(const float4*)&Qs[lg + 32][d0];
        #pragma unroll
        for (int i = 0; i < 2; ++i)
            zacc[i] += q[i].x * km4.x + q[i].y * km4.y +
                       q[i].z * km4.z + q[i].w * km4.w;
        #pragma unroll
        for (int r = 0; r < 4; ++r) {
            const float4 kva = *(const float4*)&KVs[d0 + r][mg * 4];
            const float4 kvb = *(const float4*)&KVs[d0 + r][32 + mg * 4];
            #pragma unroll
            for (int i = 0; i < 2; ++i) {
                const float qc = ((const float*)&q[i])[r];
                acc[i][0] = fmaf(qc, kva.x, acc[i][0]);
                acc[i][1] = fmaf(qc, kva.y, acc[i][1]);
                acc[i][2] = fmaf(qc, kva.z, acc[i][2]);
                acc[i][3] = fmaf(qc, kva.w, acc[i][3]);
                acc[i][4] = fmaf(qc, kvb.x, acc[i][4]);
                acc[i][5] = fmaf(qc, kvb.y, acc[i][5]);
                acc[i][6] = fmaf(qc, kvb.z, acc[i][6]);
                acc[i][7] = fmaf(qc, kvb.w, acc[i][7]);
            }
        }
    }

    #pragma unroll
    for (int i = 0; i < 2; ++i) {
        const float z = 1.f / (zacc[i] + EPS);
        const int row = l0 + lg + 32 * i;
        const size_t g = ((size_t)(n * 4096 + row) * 16 + h) * 64;
        float4 o;
        o.x = acc[i][0] * z; o.y = acc[i][1] * z;
        o.z = acc[i][2] * z; o.w = acc[i][3] * z;
        *(float4*)(out + g + mg * 4) = o;
        o.x = acc[i][4] * z; o.y = acc[i][5] * z;
        o.z = acc[i][6] * z; o.w = acc[i][7] * z;
        *(float4*)(out + g + 32 + mg * 4) = o;
    }
}

extern "C" void kernel_launch(void* const* d_in, const int* in_sizes, int n_in,
                              void* d_out, int out_size, void* d_ws, size_t ws_size,
                              hipStream_t stream) {
    const float* queries = (const float*)d_in[0];
    const float* keys    = (const float*)d_in[1];
    const float* values  = (const float*)d_in[2];
    const float* mask    = (const float*)d_in[3];
    float* out = (float*)d_out;

    const int CH = 8;   // ~10MB workspace incl. probe scratch (fits: R1 used 18MB)

    float* pkv     = (float*)d_ws;                      // [8][64][4096]
    float* pks     = pkv + (size_t)CH * 64 * 4096;      // [8][64][64]
    float* kvt     = pks + (size_t)CH * 64 * 64;        // [64][4096]
    float* ksum    = kvt + (size_t)64 * 4096;           // [64][64]
    float* pscr_ks = ksum + 64 * 64;                    // [8][64][64]
    float* pscr_v  = pscr_ks + (size_t)8 * 64 * 64;     // [8*64][256]

    kv_partial_kernel<8><<<dim3(64, CH), 256, 0, stream>>>(keys, values, mask,
                                                           pkv, pks);
    kv_reduce_kernel<<<dim3(64, 4), 256, 0, stream>>>(pkv, pks, kvt, ksum, CH);
    out_kernel<<<dim3(64, 64), 256, 0, stream>>>(queries, kvt, ksum, out);
    // diagnostic probe: half-scale staging skeleton (no fragments/MFMA)
    kv_probe_kernel<4><<<dim3(64, 8), 256, 0, stream>>>(keys, values, mask,
                                                        pscr_ks, pscr_v);
}

// Round 17
// 73.763 us; speedup vs baseline: 1.4041x; 1.1874x over previous
//
#include <hip/hip_runtime.h>

#define EPS 1e-6f

typedef __attribute__((ext_vector_type(8))) short short8;   // 8 x bf16 bits
typedef __attribute__((ext_vector_type(16))) float f32x16;  // MFMA 32x32 acc
typedef __attribute__((ext_vector_type(2))) unsigned int uint2v;

__device__ __forceinline__ float elu1(float x) {
    // elu(x) + 1  ==  x > 0 ? x + 1 : exp(x)
    return x > 0.f ? x + 1.f : __expf(x);
}

// fp32 -> bf16 bits (low 16), round-to-nearest-even
__device__ __forceinline__ unsigned f2bfu(float x) {
    unsigned u = __float_as_uint(x);
    return (u + 0x7FFFu + ((u >> 16) & 1u)) >> 16;
}

__device__ __forceinline__ float fidx(const float4& v, int i) {
    return i == 0 ? v.x : i == 1 ? v.y : i == 2 ? v.z : v.w;  // i compile-time
}

#define LGKMCNT0() asm volatile("s_waitcnt lgkmcnt(0)" ::: "memory")
// raw barrier: does NOT drain vmcnt, so global loads stay in flight.
#define BAR() do { LGKMCNT0(); __builtin_amdgcn_s_barrier(); \
                   asm volatile("" ::: "memory"); } while (0)

// ---------------------------------------------------------------------------
// Phase 1 (R17): R15 structure; fragment path rebuilt with TRANSPOSED bf16
// LDS + permuted s-index (plain ds_read_b64s — no tr-read, whose layout
// assumption failed R16). Key freedom: KV = sum_s K'[s,d]V[s,m] is order-
// invariant, so k-slot<->s assignment is arbitrary if A and B agree.
// Define s' = 4*r0 + k (thread r0 stages original rows s = r0+16k):
//   - staging: thread's 4 values per d are consecutive s' -> 1 ds_write_b64
//     per d (8 b64 writes/thread/iter, same count as R15; ~4-way banks)
//   - fragments: lane (wv,half,col) k-slot 8h+j <-> s'=16wv+8h+j -> 16
//     contiguous bytes -> 2 ds_read_b64 per fragment, 8 independent wide
//     reads per iter (was 32 latency-chained scalar b32 + cvt = the ~43us
//     R15's probe isolated). f2bf moved to staging (probe: headroom there).
// Row stride 68 ushorts = 136 B: every b64 8-B aligned.
// Fragment mapping (verified R5-R15): A row d=l&31(+32td), k=(l>>5)*8+j;
// B col m=l&31(+32tm); C/D col=l&31, row=(r&3)+8*(r>>2)+4*(l>>5).
// ---------------------------------------------------------------------------
template<int ITERS>
__global__ __launch_bounds__(256, 2) void kv_partial_kernel(
    const float* __restrict__ keys, const float* __restrict__ values,
    const float* __restrict__ mask, float* __restrict__ pkv,
    float* __restrict__ pks)
{
    __shared__ __align__(16) unsigned short KVbt[2][64][68];  // K, V: 17.4 KB
    __shared__ float cmbA[4096];     // 16 KB: ksum stage + combine buf 0
    __shared__ float cmbB[4096];     // 16 KB: combine buf 1
    __shared__ float Mls[ITERS * 64];

    const int nh = blockIdx.x, n = nh >> 4, h = nh & 15;
    const int chunk = blockIdx.y;
    const int t = threadIdx.x, wv = t >> 6, l = t & 63;
    const int half = l >> 5, col = l & 31;
    const int r0 = t >> 4, c4 = (t & 15) * 4;   // staging role

    const int s0 = chunk * (ITERS * 64);
    const float* kb = keys   + ((size_t)(n * 4096 + s0) * 16 + h) * 64;
    const float* vb = values + ((size_t)(n * 4096 + s0) * 16 + h) * 64;

    if (t < ITERS * 16)
        *(float4*)&Mls[t * 4] = *(const float4*)(mask + n * 4096 + s0 + t * 4);

    char* kvbase = (char*)&KVbt[0][0][0];
    // per-lane fragment read base: row d=col, byte col*136 + 32wv + 16half
    const char* lbase = kvbase + col * 136 + 32 * wv + 16 * half;

    f32x16 acc[2][2];
    #pragma unroll
    for (int a = 0; a < 2; ++a)
        #pragma unroll
        for (int b = 0; b < 2; ++b)
            #pragma unroll
            for (int r = 0; r < 16; ++r) acc[a][b][r] = 0.f;
    float4 ks4 = make_float4(0.f, 0.f, 0.f, 0.f);

    float4 kr[4], vr[4];
    #pragma unroll
    for (int k = 0; k < 4; ++k) {     // prologue: tile 0 (8 float4/thread)
        const size_t go = (size_t)(r0 + 16 * k) * 1024 + c4;
        kr[k] = *(const float4*)(kb + go);
        vr[k] = *(const float4*)(vb + go);
    }

    #pragma unroll
    for (int it = 0; it < ITERS; ++it) {
        BAR();   // (A) prior tile's fragment reads done; Mls visible at it==0
        // transform all 4 rows (fp32), then pack transposed bf16 writes
        float4 kt[4];
        #pragma unroll
        for (int k = 0; k < 4; ++k) {
            const float msk = Mls[it * 64 + r0 + 16 * k];
            float4 kk = kr[k];
            kk.x = elu1(kk.x) * msk; kk.y = elu1(kk.y) * msk;
            kk.z = elu1(kk.z) * msk; kk.w = elu1(kk.w) * msk;
            ks4.x += kk.x; ks4.y += kk.y; ks4.z += kk.z; ks4.w += kk.w;
            kt[k] = kk;
        }
        #pragma unroll
        for (int i = 0; i < 4; ++i) {     // d = c4+i; s' = 4*r0 + k
            uint2v kw, vw;
            kw[0] = f2bfu(fidx(kt[0], i)) | (f2bfu(fidx(kt[1], i)) << 16);
            kw[1] = f2bfu(fidx(kt[2], i)) | (f2bfu(fidx(kt[3], i)) << 16);
            vw[0] = f2bfu(fidx(vr[0], i)) | (f2bfu(fidx(vr[1], i)) << 16);
            vw[1] = f2bfu(fidx(vr[2], i)) | (f2bfu(fidx(vr[3], i)) << 16);
            const int bo = (c4 + i) * 136 + 8 * r0;
            *(uint2v*)(kvbase + bo) = kw;            // K row d
            *(uint2v*)(kvbase + 8704 + bo) = vw;     // V row d
        }
        BAR();   // (B) bf16 tiles staged & visible
        if (it + 1 < ITERS) {          // issue next tile; stays in flight
            #pragma unroll
            for (int k = 0; k < 4; ++k) {
                const size_t go = (size_t)(r0 + 16 * k + 64 * (it + 1)) * 1024 + c4;
                kr[k] = *(const float4*)(kb + go);
                vr[k] = *(const float4*)(vb + go);
            }
        }
        // fragment assembly: 8 independent ds_read_b64 (was 32 scalar + cvt)
        union UF { uint2v u[2]; short8 s; };
        UF ua, ub, uc, ud;
        ua.u[0] = *(const uint2v*)(lbase + 0);        // ka0 (d=col)
        ua.u[1] = *(const uint2v*)(lbase + 8);
        ub.u[0] = *(const uint2v*)(lbase + 4352);     // ka1 (d=col+32)
        ub.u[1] = *(const uint2v*)(lbase + 4360);
        uc.u[0] = *(const uint2v*)(lbase + 8704);     // va0 (m=col)
        uc.u[1] = *(const uint2v*)(lbase + 8712);
        ud.u[0] = *(const uint2v*)(lbase + 13056);    // va1 (m=col+32)
        ud.u[1] = *(const uint2v*)(lbase + 13064);
        acc[0][0] = __builtin_amdgcn_mfma_f32_32x32x16_bf16(ua.s, uc.s, acc[0][0], 0, 0, 0);
        acc[0][1] = __builtin_amdgcn_mfma_f32_32x32x16_bf16(ua.s, ud.s, acc[0][1], 0, 0, 0);
        acc[1][0] = __builtin_amdgcn_mfma_f32_32x32x16_bf16(ub.s, uc.s, acc[1][0], 0, 0, 0);
        acc[1][1] = __builtin_amdgcn_mfma_f32_32x32x16_bf16(ub.s, ud.s, acc[1][1], 0, 0, 0);
    }

    // ---- ksum block reduce (thread covered cols c4..c4+3 of its rows)
    BAR();
    *(float4*)&cmbA[r0 * 64 + c4] = ks4;
    BAR();
    if (t < 64) {
        float s = 0.f;
        #pragma unroll
        for (int r = 0; r < 16; ++r) s += cmbA[r * 64 + t];
        pks[((size_t)chunk * 64 + nh) * 64 + t] = s;
    }
    BAR();

    // ---- acc tree-combine across waves (R15-validated 1-phase structure)
    float* cb0 = cmbA;
    float* cb1 = cmbB;
#define FLATW(BUF)                                                         \
    { _Pragma("unroll") for (int td = 0; td < 2; ++td)                     \
      _Pragma("unroll") for (int tm = 0; tm < 2; ++tm)                     \
      _Pragma("unroll") for (int r = 0; r < 16; ++r)                       \
          BUF[((td * 2 + tm) * 16 + r) * 64 + l] = acc[td][tm][r]; }
#define FLATR(BUF)                                                         \
    { _Pragma("unroll") for (int td = 0; td < 2; ++td)                     \
      _Pragma("unroll") for (int tm = 0; tm < 2; ++tm)                     \
      _Pragma("unroll") for (int r = 0; r < 16; ++r)                       \
          acc[td][tm][r] += BUF[((td * 2 + tm) * 16 + r) * 64 + l]; }
    if (wv == 2) FLATW(cb0);
    if (wv == 3) FLATW(cb1);
    BAR();
    if (wv == 0) FLATR(cb0);
    if (wv == 1) FLATR(cb1);
    BAR();
    if (wv == 1) FLATW(cb0);
    BAR();
    if (wv == 0) {
        FLATR(cb0);
        float* pb = pkv + ((size_t)chunk * 64 + nh) * 4096;
        #pragma unroll
        for (int td = 0; td < 2; ++td)
            #pragma unroll
            for (int tm = 0; tm < 2; ++tm)
                #pragma unroll
                for (int r = 0; r < 16; ++r) {
                    const int d = 32 * td + (r & 3) + 8 * (r >> 2) + 4 * half;
                    pb[(size_t)d * 64 + 32 * tm + col] = acc[td][tm][r];
                }
    }
#undef FLATW
#undef FLATR
}

// ---------------------------------------------------------------------------
// Reduce: kvt[nh][d][m] = sum_c pkv[c][nh][d][m];  ksum[nh][d] = sum_c pks.
// ---------------------------------------------------------------------------
__global__ __launch_bounds__(256) void kv_reduce_kernel(
    const float* __restrict__ pkv, const float* __restrict__ pks,
    float* __restrict__ kvt, float* __restrict__ ksum, int CH)
{
    const int nh = blockIdx.x;
    const int f4 = blockIdx.y * 256 + threadIdx.x;   // float4 slot 0..1023
    float4 s4 = make_float4(0.f, 0.f, 0.f, 0.f);
    #pragma unroll 4
    for (int c = 0; c < CH; ++c) {
        const float4 v = *(const float4*)(pkv + ((size_t)c * 64 + nh) * 4096 + f4 * 4);
        s4.x += v.x; s4.y += v.y; s4.z += v.z; s4.w += v.w;
    }
    *(float4*)(kvt + (size_t)nh * 4096 + f4 * 4) = s4;

    if (blockIdx.y == 0 && threadIdx.x < 64) {
        float s = 0.f;
        #pragma unroll 4
        for (int c = 0; c < CH; ++c)
            s += pks[((size_t)c * 64 + nh) * 64 + threadIdx.x];
        ksum[nh * 64 + threadIdx.x] = s;
    }
}

// ---------------------------------------------------------------------------
// Phase 2: out (R8 version, ~L3-BW-bound)
// ---------------------------------------------------------------------------
__global__ __launch_bounds__(256) void out_kernel(
    const float* __restrict__ queries, const float* __restrict__ kvt,
    const float* __restrict__ ksum, float* __restrict__ out)
{
    __shared__ float Qs[64][68];    // [l][d]
    __shared__ float KVs[64][68];   // [d][m]
    __shared__ float Ksm[64];

    const int nh = blockIdx.x;
    const int n = nh >> 4, h = nh & 15;
    const int t = threadIdx.x;
    const int l0 = blockIdx.y * 64;

    #pragma unroll
    for (int k = 0; k < 4; ++k) {
        const int idx = t + k * 256;
        *(float4*)&KVs[idx >> 4][(idx & 15) * 4] =
            *(const float4*)(kvt + (size_t)nh * 4096 + idx * 4);
    }
    if (t < 64) Ksm[t] = ksum[nh * 64 + t];

    #pragma unroll
    for (int k = 0; k < 4; ++k) {
        const int idx = t + k * 256;
        const int row = idx >> 4, seg = idx & 15;
        const size_t g = ((size_t)(n * 4096 + l0 + row) * 16 + h) * 64 + seg * 4;
        float4 q4 = *(const float4*)(queries + g);
        q4.x = elu1(q4.x);
        q4.y = elu1(q4.y);
        q4.z = elu1(q4.z);
        q4.w = elu1(q4.w);
        *(float4*)&Qs[row][seg * 4] = q4;
    }
    __syncthreads();

    const int mg = t & 7;          // m cols 4mg..+3 and 32+4mg..+3
    const int lg = t >> 3;         // 0..31; rows lg, lg+32

    float acc[2][8];
    float zacc[2] = {0.f, 0.f};
    #pragma unroll
    for (int i = 0; i < 2; ++i)
        #pragma unroll
        for (int j = 0; j < 8; ++j) acc[i][j] = 0.f;

    #pragma unroll 4
    for (int d0 = 0; d0 < 64; d0 += 4) {
        const float4 km4 = *(const float4*)&Ksm[d0];
        float4 q[2];
        q[0] = *(const float4*)&Qs[lg][d0];
        q[1] = *(const float4*)&Qs[lg + 32][d0];
        #pragma unroll
        for (int i = 0; i < 2; ++i)
            zacc[i] += q[i].x * km4.x + q[i].y * km4.y +
                       q[i].z * km4.z + q[i].w * km4.w;
        #pragma unroll
        for (int r = 0; r < 4; ++r) {
            const float4 kva = *(const float4*)&KVs[d0 + r][mg * 4];
            const float4 kvb = *(const float4*)&KVs[d0 + r][32 + mg * 4];
            #pragma unroll
            for (int i = 0; i < 2; ++i) {
                const float qc = fidx(q[i], r);
                acc[i][0] = fmaf(qc, kva.x, acc[i][0]);
                acc[i][1] = fmaf(qc, kva.y, acc[i][1]);
                acc[i][2] = fmaf(qc, kva.z, acc[i][2]);
                acc[i][3] = fmaf(qc, kva.w, acc[i][3]);
                acc[i][4] = fmaf(qc, kvb.x, acc[i][4]);
                acc[i][5] = fmaf(qc, kvb.y, acc[i][5]);
                acc[i][6] = fmaf(qc, kvb.z, acc[i][6]);
                acc[i][7] = fmaf(qc, kvb.w, acc[i][7]);
            }
        }
    }

    #pragma unroll
    for (int i = 0; i < 2; ++i) {
        const float z = 1.f / (zacc[i] + EPS);
        const int row = l0 + lg + 32 * i;
        const size_t g = ((size_t)(n * 4096 + row) * 16 + h) * 64;
        float4 o;
        o.x = acc[i][0] * z; o.y = acc[i][1] * z;
        o.z = acc[i][2] * z; o.w = acc[i][3] * z;
        *(float4*)(out + g + mg * 4) = o;
        o.x = acc[i][4] * z; o.y = acc[i][5] * z;
        o.z = acc[i][6] * z; o.w = acc[i][7] * z;
        *(float4*)(out + g + 32 + mg * 4) = o;
    }
}

extern "C" void kernel_launch(void* const* d_in, const int* in_sizes, int n_in,
                              void* d_out, int out_size, void* d_ws, size_t ws_size,
                              hipStream_t stream) {
    const float* queries = (const float*)d_in[0];
    const float* keys    = (const float*)d_in[1];
    const float* values  = (const float*)d_in[2];
    const float* mask    = (const float*)d_in[3];
    float* out = (float*)d_out;

    const int CH = 8;   // ~9MB workspace (fits; R1 used 18MB)

    float* pkv  = (float*)d_ws;                      // [8][64][4096] (d,m)
    float* pks  = pkv + (size_t)CH * 64 * 4096;      // [8][64][64]
    float* kvt  = pks + (size_t)CH * 64 * 64;        // [64][4096]
    float* ksum = kvt + (size_t)64 * 4096;           // [64][64]

    kv_partial_kernel<8><<<dim3(64, CH), 256, 0, stream>>>(keys, values, mask,
                                                           pkv, pks);
    kv_reduce_kernel<<<dim3(64, 4), 256, 0, stream>>>(pkv, pks, kvt, ksum, CH);
    out_kernel<<<dim3(64, 64), 256, 0, stream>>>(queries, kvt, ksum, out);
}